// Round 4
// baseline (196.238 us; speedup 1.0000x reference)
//
#include <hip/hip_runtime.h>
#include <math.h>

// Problem constants (fixed by reference)
#define Z 2
#define NPT 256     // points per batch
#define CHN 16      // channels
#define NH 2        // heads
#define NBK 10      // key/conv radial basis
#define HD 100      // radial hidden width
#define NBV 3       // value radial basis
#define G 512       // radial table grid points (L2-resident)
// Unified table domain [0, VD]. Key/conv radials are exactly 0 beyond
// 5+5/9 (all cosine bases zero); value radial support extends to 7.5.
// At d = VD all three radials are exactly 0, so the gi>=G-1 clamp is exact.
#define VD 7.5f

__device__ __forceinline__ float swishf(float x) {
    return x / (1.0f + __expf(-x));
}

// ---------------------------------------------------------------------------
// Kernel 1 (VERBATIM round-0, verified): build radial activation tables as
// interleaved float2 {T[g], T[g+1]}; also zeroes d_out (block 0).
// reps: 0,1 = key heads (2-layer); 2 = conv (2-layer); 3,4 = value (1-layer).
// 16 grid pts per block; grid = 5*32 = 160 blocks x 128 threads.
// ---------------------------------------------------------------------------
__global__ __launch_bounds__(128)
void build_tables(const float* __restrict__ K0, const float* __restrict__ K1,
                  const float* __restrict__ C0, const float* __restrict__ C1,
                  const float* __restrict__ V0,
                  float* __restrict__ TKf, float* __restrict__ TCf,
                  float* __restrict__ TVf, float* __restrict__ out_zero) {
    int bid = blockIdx.x;
    int rep = bid >> 5;              // 0..4
    int g0  = (bid & 31) * 16;
    int t   = threadIdx.x;

    if (bid == 0) {                  // zero d_out: Z*NPT*CHN = 8192 floats
        float4* o4 = (float4*)out_zero;
        #pragma unroll
        for (int k = 0; k < 16; ++k) o4[k*128 + t] = make_float4(0.f,0.f,0.f,0.f);
    }

    if (rep >= 3) {                  // value heads: 1-layer radial
        const float* W0v = V0 + (rep - 3)*NBV*HD;
        float* Tf = TVf + (size_t)(rep - 3)*2*G*HD;
        if (t < HD) {
            #pragma unroll
            for (int k = 0; k < 16; ++k) {
                int gg = g0 + k;
                float d = gg * (VD / (float)(G-1));
                float s = 0.f;
                #pragma unroll
                for (int q = 0; q < NBV; ++q) {
                    float diff = (d - q*2.5f) * 0.4f;
                    float bq = (fabsf(diff) < 1.0f) ? __cosf(1.57079632679f*diff) : 0.f;
                    s += bq * W0v[q*HD + t];
                }
                float v = swishf(s);
                Tf[2*((size_t)gg*HD + t) + 0] = v;
                if (gg > 0) Tf[2*((size_t)(gg-1)*HD + t) + 1] = v;
            }
        }
        return;
    }

    const float* W0 = (rep == 0) ? K0 : (rep == 1) ? (K0 + NBK*HD) : C0;
    const float* W1 = (rep == 0) ? K1 : (rep == 1) ? (K1 + HD*HD)  : C1;
    float* Tf       = (rep == 0) ? TKf : (rep == 1) ? (TKf + 2*(size_t)G*HD) : TCf;

    __shared__ float s_b10[16][NBK];
    __shared__ __align__(16) float s_h1[HD*16];   // [n][k]

    if (t < 16) {
        float d = (g0 + t) * (VD / (float)(G-1));
        #pragma unroll
        for (int q = 0; q < NBK; ++q) {
            float diff = (d - q*(5.0f/9.0f)) * 1.8f;
            s_b10[t][q] = (fabsf(diff) < 1.0f) ? __cosf(1.57079632679f*diff) : 0.f;
        }
    }
    __syncthreads();
    if (t < HD) {
        int n = t;
        float w[NBK];
        #pragma unroll
        for (int q = 0; q < NBK; ++q) w[q] = W0[q*HD + n];
        #pragma unroll
        for (int k = 0; k < 16; ++k) {
            float s = 0.f;
            #pragma unroll
            for (int q = 0; q < NBK; ++q) s += s_b10[k][q] * w[q];
            s_h1[n*16 + k] = swishf(s);
        }
    }
    __syncthreads();
    if (t < HD) {
        int m = t;
        float acc[16];
        #pragma unroll
        for (int k = 0; k < 16; ++k) acc[k] = 0.f;
        const float* w1 = W1 + m;
        #pragma unroll 2
        for (int n = 0; n < HD; ++n) {
            float w = w1[n*HD];                            // coalesced across m
            const float4* hp = (const float4*)&s_h1[n*16]; // broadcast
            float4 x0 = hp[0], x1 = hp[1], x2 = hp[2], x3 = hp[3];
            acc[0]+=x0.x*w;  acc[1]+=x0.y*w;  acc[2]+=x0.z*w;  acc[3]+=x0.w*w;
            acc[4]+=x1.x*w;  acc[5]+=x1.y*w;  acc[6]+=x1.z*w;  acc[7]+=x1.w*w;
            acc[8]+=x2.x*w;  acc[9]+=x2.y*w;  acc[10]+=x2.z*w; acc[11]+=x2.w*w;
            acc[12]+=x3.x*w; acc[13]+=x3.y*w; acc[14]+=x3.z*w; acc[15]+=x3.w*w;
        }
        #pragma unroll
        for (int k = 0; k < 16; ++k) {
            float v = swishf(acc[k]);
            int gg = g0 + k;
            Tf[2*((size_t)gg*HD + m) + 0] = v;
            if (gg > 0) Tf[2*((size_t)(gg-1)*HD + m) + 1] = v;
        }
    }
}

// ---------------------------------------------------------------------------
// Kernel 1b (generalized from PROVEN build_conv_mat): fold final linear
// layers into per-grid-point 16x16 matrices from the verified activation
// tables. M[g][e] = sum_m T(g)[m] * Wf[m][e]  (exact: linearity of lerp).
// T slot 0 at (g,m) holds h(g)[m] (valid for ALL g including G-1).
// reps: 0,1 = key heads; 2 = conv; 3,4 = value.
// 4 g's per block; grid = 5*128 = 640 blocks x 256 threads.
// ---------------------------------------------------------------------------
__global__ __launch_bounds__(256)
void build_mats(const float* __restrict__ TK, const float* __restrict__ TC,
                const float* __restrict__ TV,
                const float* __restrict__ Kf, const float* __restrict__ Cf,
                const float* __restrict__ Vf,
                float* __restrict__ MK, float* __restrict__ MV,
                float* __restrict__ MC) {
    int bid = blockIdx.x;
    int rep = bid >> 7;              // 0..4
    int g0  = (bid & 127) * 4;
    int t   = threadIdx.x;

    const float *T, *Wf;
    float* M;
    if (rep == 0)      { T=TK;                    Wf=Kf;          M=MK; }
    else if (rep == 1) { T=TK+2*(size_t)G*HD;     Wf=Kf+HD*256;   M=MK+(size_t)G*256; }
    else if (rep == 2) { T=TC;                    Wf=Cf;          M=MC; }
    else if (rep == 3) { T=TV;                    Wf=Vf;          M=MV; }
    else               { T=TV+2*(size_t)G*HD;     Wf=Vf+HD*256;   M=MV+(size_t)G*256; }

    __shared__ float s_h[4][HD];
    for (int idx = t; idx < 4*HD; idx += 256) {
        int gp = idx / HD, m = idx - gp*HD;
        s_h[gp][m] = T[2*((size_t)(g0+gp)*HD + m)];   // slot 0
    }
    __syncthreads();

    float a0=0.f, a1=0.f, a2=0.f, a3=0.f;
    for (int m = 0; m < HD; ++m) {
        float w = Wf[m*256 + t];                      // coalesced over t
        a0 += s_h[0][m]*w; a1 += s_h[1][m]*w;
        a2 += s_h[2][m]*w; a3 += s_h[3][m]*w;
    }
    M[(size_t)(g0+0)*256 + t] = a0;
    M[(size_t)(g0+1)*256 + t] = a1;
    M[(size_t)(g0+2)*256 + t] = a2;
    M[(size_t)(g0+3)*256 + t] = a3;
}

// ---------------------------------------------------------------------------
// Kernel 2: fused scores + softmax + value via the folded matrix tables.
// One block per (z,h,a) = 1024 blocks x 256 threads (16 groups of 16 lanes).
// Lane i of a group owns matrix row i; group handles 16 b's serially.
// score = q^T lerp(Mk) f_b / 16; out[i] += p_b * (lerp(Mv) f_b)[i].
// Phase D mirrors the PROVEN conv consumption pattern exactly.
// ---------------------------------------------------------------------------
__global__ __launch_bounds__(256, 4)
void fused_attn(const float* __restrict__ f, const float* __restrict__ xyz,
                const float* __restrict__ Wq,
                const float* __restrict__ MK, const float* __restrict__ MV,
                float* __restrict__ attn_h) {
    int bid = blockIdx.x;            // (z*NH + h)*NPT + a
    int a  = bid & 255;
    int zh = bid >> 8;
    int h  = zh & 1;
    int z  = zh >> 1;
    int t  = threadIdx.x;

    __shared__ __align__(16) float s_f[NPT*CHN];   // 16384 B
    __shared__ int   s_gi[NPT];
    __shared__ float s_fr[NPT];
    __shared__ float s_sc[NPT];                    // scores then p
    __shared__ float s_q[16];
    __shared__ float s_red[8];
    __shared__ float s_red2[256];

    // stage features + per-b geometry
    {
        const float4* fz = (const float4*)(f + (size_t)z*NPT*CHN);
        float4* sf = (float4*)s_f;
        for (int idx = t; idx < NPT*CHN/4; idx += 256) sf[idx] = fz[idx];
    }
    {
        float ax = xyz[(z*NPT + a)*3 + 0];
        float ay = xyz[(z*NPT + a)*3 + 1];
        float az = xyz[(z*NPT + a)*3 + 2];
        int b = t;
        float dx = xyz[(z*NPT + b)*3 + 0] - ax;
        float dy = xyz[(z*NPT + b)*3 + 1] - ay;
        float dz = xyz[(z*NPT + b)*3 + 2] - az;
        float d = sqrtf(dx*dx + dy*dy + dz*dz + 1e-12f);
        float fd = d * ((float)(G-1) / VD);
        int   gi = (int)fd;
        float fr = fd - (float)gi;
        if (gi >= G-1) { gi = G-2; fr = 1.0f; }    // beyond support -> exact 0
        s_gi[b] = gi; s_fr[b] = fr;
    }
    __syncthreads();
    if (t < CHN) {       // q[o] = sum_i f[a,i] * Wq[h][o][i]
        float s = 0.f;
        const float* wq = Wq + (h*CHN + t)*CHN;
        for (int i = 0; i < CHN; ++i) s += s_f[a*CHN + i] * wq[i];
        s_q[t] = s;
    }
    __syncthreads();

    int Gr = t >> 4;     // group 0..15
    int i  = t & 15;     // matrix row owned by this lane
    float qi = s_q[i];
    int b0 = Gr*16;

    // phase B: scores
    {
        const float* base = MK + (size_t)h*G*256 + i*16;
        for (int k = 0; k < 16; ++k) {
            int b = b0 + k;
            const float* r = base + (size_t)s_gi[b]*256;
            const float4* r4 = (const float4*)r;
            float4 m0=r4[0], m1=r4[1], m2=r4[2], m3=r4[3];       // row gi
            const float4* s4 = (const float4*)(r + 256);
            float4 n0=s4[0], n1=s4[1], n2=s4[2], n3=s4[3];       // row gi+1
            float fr = s_fr[b];
            const float4* fp = (const float4*)&s_f[b*CHN];
            float4 f0=fp[0], f1=fp[1], f2=fp[2], f3=fp[3];
            float y0 = m0.x*f0.x + m0.y*f0.y + m0.z*f0.z + m0.w*f0.w
                     + m1.x*f1.x + m1.y*f1.y + m1.z*f1.z + m1.w*f1.w
                     + m2.x*f2.x + m2.y*f2.y + m2.z*f2.z + m2.w*f2.w
                     + m3.x*f3.x + m3.y*f3.y + m3.z*f3.z + m3.w*f3.w;
            float y1 = n0.x*f0.x + n0.y*f0.y + n0.z*f0.z + n0.w*f0.w
                     + n1.x*f1.x + n1.y*f1.y + n1.z*f1.z + n1.w*f1.w
                     + n2.x*f2.x + n2.y*f2.y + n2.z*f2.z + n2.w*f2.w
                     + n3.x*f3.x + n3.y*f3.y + n3.z*f3.z + n3.w*f3.w;
            float sc = qi * (y0 + fr*(y1 - y0));
            sc += __shfl_xor(sc, 1);
            sc += __shfl_xor(sc, 2);
            sc += __shfl_xor(sc, 4);
            sc += __shfl_xor(sc, 8);
            if (i == 0) s_sc[b] = sc * (1.0f/16.0f);
        }
    }
    __syncthreads();

    // phase C: softmax over 256 scores (identical to verified round-0 code)
    {
        float v = s_sc[t];
        float mx = v;
        for (int off = 32; off >= 1; off >>= 1) mx = fmaxf(mx, __shfl_xor(mx, off));
        int wid = t >> 6;
        if ((t & 63) == 0) s_red[wid] = mx;
        __syncthreads();
        mx = fmaxf(fmaxf(s_red[0], s_red[1]), fmaxf(s_red[2], s_red[3]));
        float e = __expf(v - mx);
        float s = e;
        for (int off = 32; off >= 1; off >>= 1) s += __shfl_xor(s, off);
        if ((t & 63) == 0) s_red[4 + wid] = s;
        __syncthreads();
        float tot = s_red[4] + s_red[5] + s_red[6] + s_red[7];
        s_sc[t] = e / tot;
    }
    __syncthreads();

    // phase D: out[i] = sum_b p_b * (lerp(Mv) f_b)[i]  (proven conv pattern)
    {
        const float* base = MV + (size_t)h*G*256 + i*16;
        float o = 0.f;
        for (int k = 0; k < 16; ++k) {
            int b = b0 + k;
            const float* r = base + (size_t)s_gi[b]*256;
            const float4* r4 = (const float4*)r;
            float4 m0=r4[0], m1=r4[1], m2=r4[2], m3=r4[3];
            const float4* s4 = (const float4*)(r + 256);
            float4 n0=s4[0], n1=s4[1], n2=s4[2], n3=s4[3];
            float fr = s_fr[b];
            const float4* fp = (const float4*)&s_f[b*CHN];
            float4 f0=fp[0], f1=fp[1], f2=fp[2], f3=fp[3];
            float y0 = m0.x*f0.x + m0.y*f0.y + m0.z*f0.z + m0.w*f0.w
                     + m1.x*f1.x + m1.y*f1.y + m1.z*f1.z + m1.w*f1.w
                     + m2.x*f2.x + m2.y*f2.y + m2.z*f2.z + m2.w*f2.w
                     + m3.x*f3.x + m3.y*f3.y + m3.z*f3.z + m3.w*f3.w;
            float y1 = n0.x*f0.x + n0.y*f0.y + n0.z*f0.z + n0.w*f0.w
                     + n1.x*f1.x + n1.y*f1.y + n1.z*f1.z + n1.w*f1.w
                     + n2.x*f2.x + n2.y*f2.y + n2.z*f2.z + n2.w*f2.w
                     + n3.x*f3.x + n3.y*f3.y + n3.z*f3.z + n3.w*f3.w;
            o += s_sc[b] * (y0 + fr*(y1 - y0));
        }
        s_red2[Gr*16 + i] = o;
    }
    __syncthreads();
    if (t < 16) {
        float s = 0.f;
        for (int gp = 0; gp < 16; ++gp) s += s_red2[gp*16 + t];
        attn_h[(size_t)bid*CHN + t] = s;
    }
}

// ---------------------------------------------------------------------------
// Kernel 3 (VERBATIM round-3, PROVEN): final conv via the folded MC table.
// One block per (z,a,b-half) = 1024 blocks. 16 groups of 16 lanes; lane i
// owns matrix row i; group handles 8 b's. atomicAdd (out zeroed by build).
// ---------------------------------------------------------------------------
__global__ __launch_bounds__(256)
void conv_kernel(const float* __restrict__ xyz, const float* __restrict__ MC,
                 const float* __restrict__ attn_h, float* __restrict__ out) {
    int bid = blockIdx.x;
    int bh  = bid & 1;
    int za  = bid >> 1;
    int z   = za >> 8;
    int b0g = bh * 128;
    int t   = threadIdx.x;

    __shared__ __align__(16) float s_ao[128*CHN];  // head-summed attn output
    __shared__ int   s_gi[128];
    __shared__ float s_fr[128];
    __shared__ float s_red2[256];

    for (int idx = t; idx < 128*CHN; idx += 256) {
        s_ao[idx] = attn_h[(size_t)(z*NH + 0)*NPT*CHN + b0g*CHN + idx]
                  + attn_h[(size_t)(z*NH + 1)*NPT*CHN + b0g*CHN + idx];
    }
    if (t < 128) {
        int b = b0g + t;
        float dx = xyz[(z*NPT+b)*3+0] - xyz[za*3+0];
        float dy = xyz[(z*NPT+b)*3+1] - xyz[za*3+1];
        float dz = xyz[(z*NPT+b)*3+2] - xyz[za*3+2];
        float d = sqrtf(dx*dx + dy*dy + dz*dz + 1e-12f);
        float fd = d * ((float)(G-1) / VD);
        int   gi = (int)fd;
        float fr = fd - (float)gi;
        if (gi >= G-1) { gi = G-2; fr = 1.0f; }
        s_gi[t] = gi; s_fr[t] = fr;
    }
    __syncthreads();

    int Gr = t >> 4;     // group 0..15, 8 local b's each
    int i  = t & 15;     // matrix row owned by this lane
    int l0 = Gr*8;
    {
        const float* base = MC + i*16;
        float o = 0.f;
        for (int k = 0; k < 8; ++k) {
            int l = l0 + k;
            const float* r = base + (size_t)s_gi[l]*256;
            const float4* r4 = (const float4*)r;
            float4 m0=r4[0], m1=r4[1], m2=r4[2], m3=r4[3];       // row gi
            const float4* s4 = (const float4*)(r + 256);
            float4 n0=s4[0], n1=s4[1], n2=s4[2], n3=s4[3];       // row gi+1
            float fr = s_fr[l];
            const float4* ap = (const float4*)&s_ao[l*CHN];
            float4 a0=ap[0], a1=ap[1], a2=ap[2], a3=ap[3];
            float y0 = m0.x*a0.x + m0.y*a0.y + m0.z*a0.z + m0.w*a0.w
                     + m1.x*a1.x + m1.y*a1.y + m1.z*a1.z + m1.w*a1.w
                     + m2.x*a2.x + m2.y*a2.y + m2.z*a2.z + m2.w*a2.w
                     + m3.x*a3.x + m3.y*a3.y + m3.z*a3.z + m3.w*a3.w;
            float y1 = n0.x*a0.x + n0.y*a0.y + n0.z*a0.z + n0.w*a0.w
                     + n1.x*a1.x + n1.y*a1.y + n1.z*a1.z + n1.w*a1.w
                     + n2.x*a2.x + n2.y*a2.y + n2.z*a2.z + n2.w*a2.w
                     + n3.x*a3.x + n3.y*a3.y + n3.z*a3.z + n3.w*a3.w;
            o += y0 + fr*(y1 - y0);
        }
        s_red2[Gr*16 + i] = o;
    }
    __syncthreads();
    if (t < 16) {
        float s = 0.f;
        for (int gp = 0; gp < 16; ++gp) s += s_red2[gp*16 + t];
        atomicAdd(out + (size_t)za*CHN + t, s);
    }
}

// ---------------------------------------------------------------------------
extern "C" void kernel_launch(void* const* d_in, const int* in_sizes, int n_in,
                              void* d_out, int out_size, void* d_ws, size_t ws_size,
                              hipStream_t stream) {
    const float* f   = (const float*)d_in[0];
    const float* xyz = (const float*)d_in[1];
    const float* Wq  = (const float*)d_in[2];
    const float* K0  = (const float*)d_in[3];
    const float* K1  = (const float*)d_in[4];
    const float* Kf  = (const float*)d_in[5];
    const float* V0  = (const float*)d_in[6];
    const float* Vf  = (const float*)d_in[7];
    const float* C0  = (const float*)d_in[8];
    const float* C1  = (const float*)d_in[9];
    const float* Cf  = (const float*)d_in[10];
    float* out = (float*)d_out;

    // workspace: TK2 | TC2 | TV2 (activation tables) | MK | MV | MC | attn_h
    float2* TK2    = (float2*)d_ws;
    float2* TC2    = TK2 + (size_t)NH*G*HD;
    float2* TV2    = TC2 + (size_t)G*HD;
    float*  MK     = (float*)(TV2 + (size_t)NH*G*HD);
    float*  MV     = MK + (size_t)NH*G*256;
    float*  MC     = MV + (size_t)NH*G*256;
    float*  attn_h = MC + (size_t)G*256;

    build_tables<<<160,      128, 0, stream>>>(K0, K1, C0, C1, V0,
                                               (float*)TK2, (float*)TC2,
                                               (float*)TV2, out);
    build_mats  <<<640,      256, 0, stream>>>((const float*)TK2, (const float*)TC2,
                                               (const float*)TV2, Kf, Cf, Vf,
                                               MK, MV, MC);
    fused_attn  <<<Z*NH*NPT, 256, 0, stream>>>(f, xyz, Wq, MK, MV, attn_h);
    conv_kernel <<<Z*NPT*2,  256, 0, stream>>>(xyz, MC, attn_h, out);
}

// Round 5
// 132.745 us; speedup vs baseline: 1.4783x; 1.4783x over previous
//
#include <hip/hip_runtime.h>
#include <hip/hip_fp16.h>
#include <math.h>

// Problem constants (fixed by reference)
#define Z 2
#define NPT 256     // points per batch
#define CHN 16      // channels
#define NH 2        // heads
#define NBK 10      // key/conv radial basis
#define HD 100      // radial hidden width
#define NBV 3       // value radial basis
#define G 512       // radial table grid points (L2-resident)
// Unified table domain [0, VD]. Key/conv radials are exactly 0 beyond
// 5+5/9 (all cosine bases zero); value radial support extends to 7.5.
// At d = VD all three radials are exactly 0, so the gi>=G-1 clamp is exact.
#define VD 7.5f

__device__ __forceinline__ float swishf(float x) {
    return x / (1.0f + __expf(-x));
}

// dot of 8 fp16 table elements (one uint4) with 8 fp32 features
__device__ __forceinline__ float dot8(uint4 u, float4 a, float4 b) {
    float2 c0 = __half22float2(*(const __half2*)&u.x);
    float2 c1 = __half22float2(*(const __half2*)&u.y);
    float2 c2 = __half22float2(*(const __half2*)&u.z);
    float2 c3 = __half22float2(*(const __half2*)&u.w);
    return c0.x*a.x + c0.y*a.y + c1.x*a.z + c1.y*a.w
         + c2.x*b.x + c2.y*b.y + c3.x*b.z + c3.y*b.w;
}

// ---------------------------------------------------------------------------
// Kernel 1 (VERBATIM, verified x3): build radial activation tables as
// interleaved float2 {T[g], T[g+1]}; also zeroes d_out (block 0).
// reps: 0,1 = key heads (2-layer); 2 = conv (2-layer); 3,4 = value (1-layer).
// 16 grid pts per block; grid = 5*32 = 160 blocks x 128 threads.
// ---------------------------------------------------------------------------
__global__ __launch_bounds__(128)
void build_tables(const float* __restrict__ K0, const float* __restrict__ K1,
                  const float* __restrict__ C0, const float* __restrict__ C1,
                  const float* __restrict__ V0,
                  float* __restrict__ TKf, float* __restrict__ TCf,
                  float* __restrict__ TVf, float* __restrict__ out_zero) {
    int bid = blockIdx.x;
    int rep = bid >> 5;              // 0..4
    int g0  = (bid & 31) * 16;
    int t   = threadIdx.x;

    if (bid == 0) {                  // zero d_out: Z*NPT*CHN = 8192 floats
        float4* o4 = (float4*)out_zero;
        #pragma unroll
        for (int k = 0; k < 16; ++k) o4[k*128 + t] = make_float4(0.f,0.f,0.f,0.f);
    }

    if (rep >= 3) {                  // value heads: 1-layer radial
        const float* W0v = V0 + (rep - 3)*NBV*HD;
        float* Tf = TVf + (size_t)(rep - 3)*2*G*HD;
        if (t < HD) {
            #pragma unroll
            for (int k = 0; k < 16; ++k) {
                int gg = g0 + k;
                float d = gg * (VD / (float)(G-1));
                float s = 0.f;
                #pragma unroll
                for (int q = 0; q < NBV; ++q) {
                    float diff = (d - q*2.5f) * 0.4f;
                    float bq = (fabsf(diff) < 1.0f) ? __cosf(1.57079632679f*diff) : 0.f;
                    s += bq * W0v[q*HD + t];
                }
                float v = swishf(s);
                Tf[2*((size_t)gg*HD + t) + 0] = v;
                if (gg > 0) Tf[2*((size_t)(gg-1)*HD + t) + 1] = v;
            }
        }
        return;
    }

    const float* W0 = (rep == 0) ? K0 : (rep == 1) ? (K0 + NBK*HD) : C0;
    const float* W1 = (rep == 0) ? K1 : (rep == 1) ? (K1 + HD*HD)  : C1;
    float* Tf       = (rep == 0) ? TKf : (rep == 1) ? (TKf + 2*(size_t)G*HD) : TCf;

    __shared__ float s_b10[16][NBK];
    __shared__ __align__(16) float s_h1[HD*16];   // [n][k]

    if (t < 16) {
        float d = (g0 + t) * (VD / (float)(G-1));
        #pragma unroll
        for (int q = 0; q < NBK; ++q) {
            float diff = (d - q*(5.0f/9.0f)) * 1.8f;
            s_b10[t][q] = (fabsf(diff) < 1.0f) ? __cosf(1.57079632679f*diff) : 0.f;
        }
    }
    __syncthreads();
    if (t < HD) {
        int n = t;
        float w[NBK];
        #pragma unroll
        for (int q = 0; q < NBK; ++q) w[q] = W0[q*HD + n];
        #pragma unroll
        for (int k = 0; k < 16; ++k) {
            float s = 0.f;
            #pragma unroll
            for (int q = 0; q < NBK; ++q) s += s_b10[k][q] * w[q];
            s_h1[n*16 + k] = swishf(s);
        }
    }
    __syncthreads();
    if (t < HD) {
        int m = t;
        float acc[16];
        #pragma unroll
        for (int k = 0; k < 16; ++k) acc[k] = 0.f;
        const float* w1 = W1 + m;
        #pragma unroll 2
        for (int n = 0; n < HD; ++n) {
            float w = w1[n*HD];                            // coalesced across m
            const float4* hp = (const float4*)&s_h1[n*16]; // broadcast
            float4 x0 = hp[0], x1 = hp[1], x2 = hp[2], x3 = hp[3];
            acc[0]+=x0.x*w;  acc[1]+=x0.y*w;  acc[2]+=x0.z*w;  acc[3]+=x0.w*w;
            acc[4]+=x1.x*w;  acc[5]+=x1.y*w;  acc[6]+=x1.z*w;  acc[7]+=x1.w*w;
            acc[8]+=x2.x*w;  acc[9]+=x2.y*w;  acc[10]+=x2.z*w; acc[11]+=x2.w*w;
            acc[12]+=x3.x*w; acc[13]+=x3.y*w; acc[14]+=x3.z*w; acc[15]+=x3.w*w;
        }
        #pragma unroll
        for (int k = 0; k < 16; ++k) {
            float v = swishf(acc[k]);
            int gg = g0 + k;
            Tf[2*((size_t)gg*HD + m) + 0] = v;
            if (gg > 0) Tf[2*((size_t)(gg-1)*HD + m) + 1] = v;
        }
    }
}

// ---------------------------------------------------------------------------
// Kernel 1b (PROVEN fold, new output format): fold final linear layers into
// per-grid-point 16x16 matrices from the verified activation tables.
// M[g][i][j] = sum_m T(g)[m] * Wf[m][i*16+j]  (exact: linearity of lerp).
// Output: fp16, chunk-interleaved within each 256-half row:
//   element (i,j) -> half offset (c*16 + i)*8 + e,  c=j>>3, e=j&7
// so consumer lane i's chunk-c uint4 load (16 lanes x 16B) is contiguous.
// 4 g's per block; grid = 5*128 = 640 blocks x 256 threads.
// ---------------------------------------------------------------------------
__global__ __launch_bounds__(256)
void build_mats(const float* __restrict__ TK, const float* __restrict__ TC,
                const float* __restrict__ TV,
                const float* __restrict__ Kf, const float* __restrict__ Cf,
                const float* __restrict__ Vf,
                __half* __restrict__ MK, __half* __restrict__ MV,
                __half* __restrict__ MC) {
    int bid = blockIdx.x;
    int rep = bid >> 7;              // 0..4
    int g0  = (bid & 127) * 4;
    int t   = threadIdx.x;

    const float *T, *Wf;
    __half* M;
    if (rep == 0)      { T=TK;                    Wf=Kf;          M=MK; }
    else if (rep == 1) { T=TK+2*(size_t)G*HD;     Wf=Kf+HD*256;   M=MK+(size_t)G*256; }
    else if (rep == 2) { T=TC;                    Wf=Cf;          M=MC; }
    else if (rep == 3) { T=TV;                    Wf=Vf;          M=MV; }
    else               { T=TV+2*(size_t)G*HD;     Wf=Vf+HD*256;   M=MV+(size_t)G*256; }

    __shared__ float s_h[4][HD];
    for (int idx = t; idx < 4*HD; idx += 256) {
        int gp = idx / HD, m = idx - gp*HD;
        s_h[gp][m] = T[2*((size_t)(g0+gp)*HD + m)];   // slot 0
    }
    __syncthreads();

    float a0=0.f, a1=0.f, a2=0.f, a3=0.f;
    for (int m = 0; m < HD; ++m) {
        float w = Wf[m*256 + t];                      // coalesced over t
        a0 += s_h[0][m]*w; a1 += s_h[1][m]*w;
        a2 += s_h[2][m]*w; a3 += s_h[3][m]*w;
    }
    int i = t >> 4, j = t & 15;
    int c = j >> 3, e = j & 7;
    size_t off = (size_t)(c*16 + i)*8 + e;            // within 256-half row
    M[(size_t)(g0+0)*256 + off] = __float2half(a0);
    M[(size_t)(g0+1)*256 + off] = __float2half(a1);
    M[(size_t)(g0+2)*256 + off] = __float2half(a2);
    M[(size_t)(g0+3)*256 + off] = __float2half(a3);
}

// ---------------------------------------------------------------------------
// Kernel 2 (PROVEN structure; loads now fp16 + coalesced): fused scores +
// softmax + value via folded matrix tables. One block per (z,h,a) = 1024
// blocks x 256 threads (16 groups of 16 lanes). Lane i owns matrix row i.
// Per (group,b): 4 uint4 loads, each 16 lanes x 16B = 256B contiguous.
// ---------------------------------------------------------------------------
__global__ __launch_bounds__(256, 4)
void fused_attn(const float* __restrict__ f, const float* __restrict__ xyz,
                const float* __restrict__ Wq,
                const __half* __restrict__ MK, const __half* __restrict__ MV,
                float* __restrict__ attn_h) {
    int bid = blockIdx.x;            // (z*NH + h)*NPT + a
    int a  = bid & 255;
    int zh = bid >> 8;
    int h  = zh & 1;
    int z  = zh >> 1;
    int t  = threadIdx.x;

    __shared__ __align__(16) float s_f[NPT*CHN];   // 16384 B
    __shared__ int   s_gi[NPT];
    __shared__ float s_fr[NPT];
    __shared__ float s_sc[NPT];                    // scores then p
    __shared__ float s_q[16];
    __shared__ float s_red[8];
    __shared__ float s_red2[256];

    // stage features + per-b geometry
    {
        const float4* fz = (const float4*)(f + (size_t)z*NPT*CHN);
        float4* sf = (float4*)s_f;
        for (int idx = t; idx < NPT*CHN/4; idx += 256) sf[idx] = fz[idx];
    }
    {
        float ax = xyz[(z*NPT + a)*3 + 0];
        float ay = xyz[(z*NPT + a)*3 + 1];
        float az = xyz[(z*NPT + a)*3 + 2];
        int b = t;
        float dx = xyz[(z*NPT + b)*3 + 0] - ax;
        float dy = xyz[(z*NPT + b)*3 + 1] - ay;
        float dz = xyz[(z*NPT + b)*3 + 2] - az;
        float d = sqrtf(dx*dx + dy*dy + dz*dz + 1e-12f);
        float fd = d * ((float)(G-1) / VD);
        int   gi = (int)fd;
        float fr = fd - (float)gi;
        if (gi >= G-1) { gi = G-2; fr = 1.0f; }    // beyond support -> exact 0
        s_gi[b] = gi; s_fr[b] = fr;
    }
    __syncthreads();
    if (t < CHN) {       // q[o] = sum_i f[a,i] * Wq[h][o][i]
        float s = 0.f;
        const float* wq = Wq + (h*CHN + t)*CHN;
        for (int i = 0; i < CHN; ++i) s += s_f[a*CHN + i] * wq[i];
        s_q[t] = s;
    }
    __syncthreads();

    int Gr = t >> 4;     // group 0..15
    int i  = t & 15;     // matrix row owned by this lane
    float qi = s_q[i];
    int b0 = Gr*16;

    // phase B: scores
    {
        const __half* basek = MK + (size_t)h*G*256;
        for (int k = 0; k < 16; ++k) {
            int b = b0 + k;
            const uint4* p = (const uint4*)(basek + (size_t)s_gi[b]*256) + i;
            uint4 q0 = p[0];       // row gi,   j 0..7
            uint4 q1 = p[16];      // row gi,   j 8..15
            uint4 q2 = p[32];      // row gi+1, j 0..7
            uint4 q3 = p[48];      // row gi+1, j 8..15
            float fr = s_fr[b];
            const float4* fp = (const float4*)&s_f[b*CHN];
            float4 f0=fp[0], f1=fp[1], f2=fp[2], f3=fp[3];
            float y0 = dot8(q0, f0, f1) + dot8(q1, f2, f3);
            float y1 = dot8(q2, f0, f1) + dot8(q3, f2, f3);
            float sc = qi * (y0 + fr*(y1 - y0));
            sc += __shfl_xor(sc, 1);
            sc += __shfl_xor(sc, 2);
            sc += __shfl_xor(sc, 4);
            sc += __shfl_xor(sc, 8);
            if (i == 0) s_sc[b] = sc * (1.0f/16.0f);
        }
    }
    __syncthreads();

    // phase C: softmax over 256 scores (verified round-0 code)
    {
        float v = s_sc[t];
        float mx = v;
        for (int off = 32; off >= 1; off >>= 1) mx = fmaxf(mx, __shfl_xor(mx, off));
        int wid = t >> 6;
        if ((t & 63) == 0) s_red[wid] = mx;
        __syncthreads();
        mx = fmaxf(fmaxf(s_red[0], s_red[1]), fmaxf(s_red[2], s_red[3]));
        float e = __expf(v - mx);
        float s = e;
        for (int off = 32; off >= 1; off >>= 1) s += __shfl_xor(s, off);
        if ((t & 63) == 0) s_red[4 + wid] = s;
        __syncthreads();
        float tot = s_red[4] + s_red[5] + s_red[6] + s_red[7];
        s_sc[t] = e / tot;
    }
    __syncthreads();

    // phase D: out[i] = sum_b p_b * (lerp(Mv) f_b)[i]
    {
        const __half* basev = MV + (size_t)h*G*256;
        float o = 0.f;
        for (int k = 0; k < 16; ++k) {
            int b = b0 + k;
            const uint4* p = (const uint4*)(basev + (size_t)s_gi[b]*256) + i;
            uint4 q0 = p[0];
            uint4 q1 = p[16];
            uint4 q2 = p[32];
            uint4 q3 = p[48];
            float fr = s_fr[b];
            const float4* fp = (const float4*)&s_f[b*CHN];
            float4 f0=fp[0], f1=fp[1], f2=fp[2], f3=fp[3];
            float y0 = dot8(q0, f0, f1) + dot8(q1, f2, f3);
            float y1 = dot8(q2, f0, f1) + dot8(q3, f2, f3);
            o += s_sc[b] * (y0 + fr*(y1 - y0));
        }
        s_red2[Gr*16 + i] = o;
    }
    __syncthreads();
    if (t < 16) {
        float s = 0.f;
        for (int gp = 0; gp < 16; ++gp) s += s_red2[gp*16 + t];
        attn_h[(size_t)bid*CHN + t] = s;
    }
}

// ---------------------------------------------------------------------------
// Kernel 3 (PROVEN structure; loads now fp16 + coalesced): final conv via
// folded MC table. One block per (z,a,b-half) = 1024 blocks. atomicAdd.
// ---------------------------------------------------------------------------
__global__ __launch_bounds__(256)
void conv_kernel(const float* __restrict__ xyz, const __half* __restrict__ MC,
                 const float* __restrict__ attn_h, float* __restrict__ out) {
    int bid = blockIdx.x;
    int bh  = bid & 1;
    int za  = bid >> 1;
    int z   = za >> 8;
    int b0g = bh * 128;
    int t   = threadIdx.x;

    __shared__ __align__(16) float s_ao[128*CHN];  // head-summed attn output
    __shared__ int   s_gi[128];
    __shared__ float s_fr[128];
    __shared__ float s_red2[256];

    for (int idx = t; idx < 128*CHN; idx += 256) {
        s_ao[idx] = attn_h[(size_t)(z*NH + 0)*NPT*CHN + b0g*CHN + idx]
                  + attn_h[(size_t)(z*NH + 1)*NPT*CHN + b0g*CHN + idx];
    }
    if (t < 128) {
        int b = b0g + t;
        float dx = xyz[(z*NPT+b)*3+0] - xyz[za*3+0];
        float dy = xyz[(z*NPT+b)*3+1] - xyz[za*3+1];
        float dz = xyz[(z*NPT+b)*3+2] - xyz[za*3+2];
        float d = sqrtf(dx*dx + dy*dy + dz*dz + 1e-12f);
        float fd = d * ((float)(G-1) / VD);
        int   gi = (int)fd;
        float fr = fd - (float)gi;
        if (gi >= G-1) { gi = G-2; fr = 1.0f; }
        s_gi[t] = gi; s_fr[t] = fr;
    }
    __syncthreads();

    int Gr = t >> 4;     // group 0..15, 8 local b's each
    int i  = t & 15;     // matrix row owned by this lane
    int l0 = Gr*8;
    {
        float o = 0.f;
        for (int k = 0; k < 8; ++k) {
            int l = l0 + k;
            const uint4* p = (const uint4*)(MC + (size_t)s_gi[l]*256) + i;
            uint4 q0 = p[0];
            uint4 q1 = p[16];
            uint4 q2 = p[32];
            uint4 q3 = p[48];
            float fr = s_fr[l];
            const float4* ap = (const float4*)&s_ao[l*CHN];
            float4 a0=ap[0], a1=ap[1], a2=ap[2], a3=ap[3];
            float y0 = dot8(q0, a0, a1) + dot8(q1, a2, a3);
            float y1 = dot8(q2, a0, a1) + dot8(q3, a2, a3);
            o += y0 + fr*(y1 - y0);
        }
        s_red2[Gr*16 + i] = o;
    }
    __syncthreads();
    if (t < 16) {
        float s = 0.f;
        for (int gp = 0; gp < 16; ++gp) s += s_red2[gp*16 + t];
        atomicAdd(out + (size_t)za*CHN + t, s);
    }
}

// ---------------------------------------------------------------------------
extern "C" void kernel_launch(void* const* d_in, const int* in_sizes, int n_in,
                              void* d_out, int out_size, void* d_ws, size_t ws_size,
                              hipStream_t stream) {
    const float* f   = (const float*)d_in[0];
    const float* xyz = (const float*)d_in[1];
    const float* Wq  = (const float*)d_in[2];
    const float* K0  = (const float*)d_in[3];
    const float* K1  = (const float*)d_in[4];
    const float* Kf  = (const float*)d_in[5];
    const float* V0  = (const float*)d_in[6];
    const float* Vf  = (const float*)d_in[7];
    const float* C0  = (const float*)d_in[8];
    const float* C1  = (const float*)d_in[9];
    const float* Cf  = (const float*)d_in[10];
    float* out = (float*)d_out;

    // workspace: TK2 | TC2 | TV2 (fp32 activation tables) |
    //            MK | MV | MC (fp16 matrix tables, swizzled) | attn_h
    float2* TK2    = (float2*)d_ws;
    float2* TC2    = TK2 + (size_t)NH*G*HD;
    float2* TV2    = TC2 + (size_t)G*HD;
    __half* MK     = (__half*)(TV2 + (size_t)NH*G*HD);
    __half* MV     = MK + (size_t)NH*G*256;
    __half* MC     = MV + (size_t)NH*G*256;
    float*  attn_h = (float*)(MC + (size_t)G*256);

    build_tables<<<160,      128, 0, stream>>>(K0, K1, C0, C1, V0,
                                               (float*)TK2, (float*)TC2,
                                               (float*)TV2, out);
    build_mats  <<<640,      256, 0, stream>>>((const float*)TK2, (const float*)TC2,
                                               (const float*)TV2, Kf, Cf, Vf,
                                               MK, MV, MC);
    fused_attn  <<<Z*NH*NPT, 256, 0, stream>>>(f, xyz, Wq, MK, MV, attn_h);
    conv_kernel <<<Z*NPT*2,  256, 0, stream>>>(xyz, MC, attn_h, out);
}